// Round 6
// baseline (229.110 us; speedup 1.0000x reference)
//
#include <hip/hip_runtime.h>

// Haar DWT2: x (8,64,512,512) fp32 -> (ll,lh,hl,hh) each (8,64,256,256),
// concatenated flat in d_out. Memory-bound (1.074 GB total traffic).
//
// R3 structure (best: 198.8us): each thread item = (plane, out_row, col-quad),
// reads 8 input cols from rows 2i/2i+1 (4x 16B nt loads), writes one 16B nt
// store per subband. This round: exact-divisible grid (4096x256 threads,
// 8 items/thread), compile-time trip count, no bounds check, #pragma unroll 4
// so the compiler can software-pipeline 4 independent items' loads.

typedef float v4f __attribute__((ext_vector_type(4)));

__device__ __forceinline__ void dwt_item(const float* __restrict__ x,
                                         float* __restrict__ oll,
                                         float* __restrict__ olh,
                                         float* __restrict__ ohl,
                                         float* __restrict__ ohh,
                                         int idx)
{
    // work item: plane (9b) | out_row i (8b) | col-quad jq (6b)
    int plane = idx >> 14;
    int rem   = idx & 16383;
    int i     = rem >> 6;
    int jq    = rem & 63;

    long long in_off = (long long)plane * 262144 + i * 1024 + jq * 8;
    v4f r0a = __builtin_nontemporal_load(reinterpret_cast<const v4f*>(x + in_off));
    v4f r0b = __builtin_nontemporal_load(reinterpret_cast<const v4f*>(x + in_off + 4));
    v4f r1a = __builtin_nontemporal_load(reinterpret_cast<const v4f*>(x + in_off + 512));
    v4f r1b = __builtin_nontemporal_load(reinterpret_cast<const v4f*>(x + in_off + 516));

    v4f ll, lh, hl, hh;
    {
        float s0 = r0a.x + r0a.y, d0 = r0a.x - r0a.y;
        float s1 = r1a.x + r1a.y, d1 = r1a.x - r1a.y;
        ll.x = (s0 + s1) * 0.5f; lh.x = (s0 - s1) * 0.5f;
        hl.x = (d0 + d1) * 0.5f; hh.x = (d0 - d1) * 0.5f;
    }
    {
        float s0 = r0a.z + r0a.w, d0 = r0a.z - r0a.w;
        float s1 = r1a.z + r1a.w, d1 = r1a.z - r1a.w;
        ll.y = (s0 + s1) * 0.5f; lh.y = (s0 - s1) * 0.5f;
        hl.y = (d0 + d1) * 0.5f; hh.y = (d0 - d1) * 0.5f;
    }
    {
        float s0 = r0b.x + r0b.y, d0 = r0b.x - r0b.y;
        float s1 = r1b.x + r1b.y, d1 = r1b.x - r1b.y;
        ll.z = (s0 + s1) * 0.5f; lh.z = (s0 - s1) * 0.5f;
        hl.z = (d0 + d1) * 0.5f; hh.z = (d0 - d1) * 0.5f;
    }
    {
        float s0 = r0b.z + r0b.w, d0 = r0b.z - r0b.w;
        float s1 = r1b.z + r1b.w, d1 = r1b.z - r1b.w;
        ll.w = (s0 + s1) * 0.5f; lh.w = (s0 - s1) * 0.5f;
        hl.w = (d0 + d1) * 0.5f; hh.w = (d0 - d1) * 0.5f;
    }

    long long o = (long long)plane * 65536 + i * 256 + jq * 4;
    __builtin_nontemporal_store(ll, reinterpret_cast<v4f*>(oll + o));
    __builtin_nontemporal_store(lh, reinterpret_cast<v4f*>(olh + o));
    __builtin_nontemporal_store(hl, reinterpret_cast<v4f*>(ohl + o));
    __builtin_nontemporal_store(hh, reinterpret_cast<v4f*>(ohh + o));
}

__global__ __launch_bounds__(256) void dwt2_haar_kernel(
    const float* __restrict__ x, float* __restrict__ out)
{
    const long long OUT_SZ = 512LL * 65536LL;
    const int STRIDE = 4096 * 256;      // total threads
    // total items = 512*256*64 = 8,388,608 = STRIDE * 8 exactly.

    float* __restrict__ oll = out;
    float* __restrict__ olh = out + OUT_SZ;
    float* __restrict__ ohl = out + 2 * OUT_SZ;
    float* __restrict__ ohh = out + 3 * OUT_SZ;

    int tid = blockIdx.x * blockDim.x + threadIdx.x;

#pragma unroll 4
    for (int k = 0; k < 8; ++k) {
        dwt_item(x, oll, olh, ohl, ohh, tid + k * STRIDE);
    }
}

extern "C" void kernel_launch(void* const* d_in, const int* in_sizes, int n_in,
                              void* d_out, int out_size, void* d_ws, size_t ws_size,
                              hipStream_t stream) {
    const float* x = (const float*)d_in[0];
    float* out = (float*)d_out;

    dwt2_haar_kernel<<<4096, 256, 0, stream>>>(x, out);
}

// Round 7
// 198.782 us; speedup vs baseline: 1.1526x; 1.1526x over previous
//
#include <hip/hip_runtime.h>

// Haar DWT2: x (8,64,512,512) fp32 -> (ll,lh,hl,hh) each (8,64,256,256),
// concatenated flat in d_out. Memory-bound (1.074 GB traffic; best 198.8us
// = 5.40 TB/s = 86% of m13 float4-copy ceiling 6.29 TB/s).
//
// Each work item = (plane, out_row, col-quad): reads 8 input cols from rows
// 2i/2i+1 (4x 16B nt loads), writes one 16B nt store per subband.
// Grid-stride loop, 2048 blocks x 256 threads, 2-way unroll.
// Known-failed variants: float2 stores (R0, +7%), shfl-exchange wave-
// contiguous reads (R4, -1.5%), unroll-4 fixed trip count (R5, -15%).

typedef float v4f __attribute__((ext_vector_type(4)));

__device__ __forceinline__ void dwt_item(const float* __restrict__ x,
                                         float* __restrict__ oll,
                                         float* __restrict__ olh,
                                         float* __restrict__ ohl,
                                         float* __restrict__ ohh,
                                         int idx)
{
    // work item: plane (9b) | out_row i (8b) | col-quad jq (6b)
    int plane = idx >> 14;
    int rem   = idx & 16383;
    int i     = rem >> 6;
    int jq    = rem & 63;

    long long in_off = (long long)plane * 262144 + i * 1024 + jq * 8;
    v4f r0a = __builtin_nontemporal_load(reinterpret_cast<const v4f*>(x + in_off));
    v4f r0b = __builtin_nontemporal_load(reinterpret_cast<const v4f*>(x + in_off + 4));
    v4f r1a = __builtin_nontemporal_load(reinterpret_cast<const v4f*>(x + in_off + 512));
    v4f r1b = __builtin_nontemporal_load(reinterpret_cast<const v4f*>(x + in_off + 516));

    v4f ll, lh, hl, hh;
    {
        float s0 = r0a.x + r0a.y, d0 = r0a.x - r0a.y;
        float s1 = r1a.x + r1a.y, d1 = r1a.x - r1a.y;
        ll.x = (s0 + s1) * 0.5f; lh.x = (s0 - s1) * 0.5f;
        hl.x = (d0 + d1) * 0.5f; hh.x = (d0 - d1) * 0.5f;
    }
    {
        float s0 = r0a.z + r0a.w, d0 = r0a.z - r0a.w;
        float s1 = r1a.z + r1a.w, d1 = r1a.z - r1a.w;
        ll.y = (s0 + s1) * 0.5f; lh.y = (s0 - s1) * 0.5f;
        hl.y = (d0 + d1) * 0.5f; hh.y = (d0 - d1) * 0.5f;
    }
    {
        float s0 = r0b.x + r0b.y, d0 = r0b.x - r0b.y;
        float s1 = r1b.x + r1b.y, d1 = r1b.x - r1b.y;
        ll.z = (s0 + s1) * 0.5f; lh.z = (s0 - s1) * 0.5f;
        hl.z = (d0 + d1) * 0.5f; hh.z = (d0 - d1) * 0.5f;
    }
    {
        float s0 = r0b.z + r0b.w, d0 = r0b.z - r0b.w;
        float s1 = r1b.z + r1b.w, d1 = r1b.z - r1b.w;
        ll.w = (s0 + s1) * 0.5f; lh.w = (s0 - s1) * 0.5f;
        hl.w = (d0 + d1) * 0.5f; hh.w = (d0 - d1) * 0.5f;
    }

    long long o = (long long)plane * 65536 + i * 256 + jq * 4;
    __builtin_nontemporal_store(ll, reinterpret_cast<v4f*>(oll + o));
    __builtin_nontemporal_store(lh, reinterpret_cast<v4f*>(olh + o));
    __builtin_nontemporal_store(hl, reinterpret_cast<v4f*>(ohl + o));
    __builtin_nontemporal_store(hh, reinterpret_cast<v4f*>(ohh + o));
}

__global__ __launch_bounds__(256) void dwt2_haar_kernel(
    const float* __restrict__ x, float* __restrict__ out, int total)
{
    const long long OUT_SZ = 512LL * 65536LL;

    float* __restrict__ oll = out;
    float* __restrict__ olh = out + OUT_SZ;
    float* __restrict__ ohl = out + 2 * OUT_SZ;
    float* __restrict__ ohh = out + 3 * OUT_SZ;

    const int stride = gridDim.x * blockDim.x;
    int idx = blockIdx.x * blockDim.x + threadIdx.x;

    // 2-way unroll: total = 8,388,608, stride = 524,288 -> 16 items/thread,
    // 8 unrolled trips. No remainder for this fixed shape.
    for (; idx + stride < total; idx += 2 * stride) {
        dwt_item(x, oll, olh, ohl, ohh, idx);
        dwt_item(x, oll, olh, ohl, ohh, idx + stride);
    }
    for (; idx < total; idx += stride) {
        dwt_item(x, oll, olh, ohl, ohh, idx);
    }
}

extern "C" void kernel_launch(void* const* d_in, const int* in_sizes, int n_in,
                              void* d_out, int out_size, void* d_ws, size_t ws_size,
                              hipStream_t stream) {
    const float* x = (const float*)d_in[0];
    float* out = (float*)d_out;

    const int total = 512 * 256 * 64;   // 8,388,608 work items
    const int block = 256;
    const int grid = 2048;

    dwt2_haar_kernel<<<grid, block, 0, stream>>>(x, out, total);
}